// Round 9
// baseline (596.635 us; speedup 1.0000x reference)
//
#include <hip/hip_runtime.h>
#include <cstdint>
#include <cstddef>

// ---------------------------------------------------------------------------
// GAT x2 + LayerNorm on MI355X.
// Interface (established R0-R7): inputs fp32, edge_index int32, output fp32.
// R8: MFMA bf16 GEMMs. R9: factored softmax -> per-edge alpha precompute;
// aggregation is pure weighted gather (no exp/rescale in the hot loop).
// ---------------------------------------------------------------------------

constexpr int NNODES = 50000;

typedef unsigned short bf16_t;
typedef __attribute__((ext_vector_type(8))) short bf16x8;
typedef __attribute__((ext_vector_type(4))) float f32x4;

__device__ __forceinline__ float bf2f(bf16_t b) {
  return __uint_as_float(((unsigned int)b) << 16);
}
__device__ __forceinline__ bf16_t f2bf(float f) {
  unsigned int u = __float_as_uint(f);
  u += 0x7fffu + ((u >> 16) & 1u);   // round to nearest even
  return (bf16_t)(u >> 16);
}
__device__ __forceinline__ float4 bf4_to_f4(ushort4 v) {
  return make_float4(bf2f(v.x), bf2f(v.y), bf2f(v.z), bf2f(v.w));
}
__device__ __forceinline__ ushort4 f4_to_bf4(float4 v) {
  return make_ushort4(f2bf(v.x), f2bf(v.y), f2bf(v.z), f2bf(v.w));
}
__device__ __forceinline__ float lrelu(float x) { return x > 0.f ? x : 0.2f * x; }
__device__ __forceinline__ int clampi(int v, int lo, int hi) {
  return v < lo ? lo : (v > hi ? hi : v);
}
__device__ __forceinline__ int load_edge(const void* ei, int mode, int idx) {
  if (mode) return (int)((const long long*)ei)[idx];
  return ((const int*)ei)[idx];
}

// ------------------------------ prep kernels -------------------------------

__global__ void convert_x_kernel(const float* __restrict__ x, bf16_t* __restrict__ xb,
                                 int n4) {
  int i = blockIdx.x * blockDim.x + threadIdx.x;
  if (i >= n4) return;
  float4 v = *(const float4*)(x + 4 * (size_t)i);
  *(ushort4*)(xb + 4 * (size_t)i) = f4_to_bf4(v);
}

// Wt[n][k] = bf16(W[k][n]);  grid = NC blocks, block = K threads
template <int K, int NC>
__global__ void transpose_w_kernel(const float* __restrict__ W, bf16_t* __restrict__ Wt) {
  int n = blockIdx.x;
  int k = threadIdx.x;
  Wt[(size_t)n * K + k] = f2bf(W[(size_t)k * NC + n]);
}

// --------------------------- edge dtype detection --------------------------
__global__ void detect_kernel(const int* __restrict__ ei32, int* __restrict__ mode) {
  __shared__ int nz;
  if (threadIdx.x == 0) nz = 0;
  __syncthreads();
  int idx = 2 * threadIdx.x + 1;
  if (ei32[idx] != 0) atomicAdd(&nz, 1);
  __syncthreads();
  if (threadIdx.x == 0) mode[0] = (nz == 0) ? 1 : 0;
}

// ------------------------------- CSR build ---------------------------------

__global__ void zero_kernel(int* __restrict__ p, int n) {
  int i = blockIdx.x * blockDim.x + threadIdx.x;
  if (i < n) p[i] = 0;
}

__global__ void hist_kernel(const void* __restrict__ ei, const int* __restrict__ modep,
                            int* __restrict__ counts, int e0, int et) {
  int e = blockIdx.x * blockDim.x + threadIdx.x;
  if (e >= et) return;
  int mode = modep[0];
  int dst = (e < e0) ? load_edge(ei, mode, e0 + e) : (e - e0);
  dst = clampi(dst, 0, NNODES - 1);
  atomicAdd(&counts[dst], 1);
}

__global__ __launch_bounds__(1024) void scan1_kernel(const int* __restrict__ counts,
                                                     int* __restrict__ rowptr,
                                                     int* __restrict__ bsums) {
  __shared__ int sm[1024];
  int t = threadIdx.x;
  int i = blockIdx.x * 1024 + t;
  sm[t] = (i < NNODES) ? counts[i] : 0;
  __syncthreads();
  for (int off = 1; off < 1024; off <<= 1) {
    int u = (t >= off) ? sm[t - off] : 0;
    __syncthreads();
    sm[t] += u;
    __syncthreads();
  }
  if (i < NNODES) rowptr[i + 1] = sm[t];
  if (t == 1023) bsums[blockIdx.x] = sm[1023];
}

__global__ void scan2_kernel(const int* __restrict__ bsums, int* __restrict__ boff,
                             int nb, int* __restrict__ rowptr, int* __restrict__ cursor) {
  if (threadIdx.x == 0 && blockIdx.x == 0) {
    int run = 0;
    for (int b = 0; b < nb; ++b) { boff[b] = run; run += bsums[b]; }
    rowptr[0] = 0;
    cursor[0] = 0;
  }
}

__global__ __launch_bounds__(1024) void scan3_kernel(const int* __restrict__ boff,
                                                     int* __restrict__ rowptr,
                                                     int* __restrict__ cursor) {
  int i = blockIdx.x * 1024 + threadIdx.x;
  if (i < NNODES) {
    int v = rowptr[i + 1] + boff[blockIdx.x];
    rowptr[i + 1] = v;
    cursor[i + 1] = v;
  }
}

__global__ void fill_kernel(const void* __restrict__ ei, const int* __restrict__ modep,
                            int* __restrict__ cursor, int* __restrict__ col,
                            int e0, int et) {
  int e = blockIdx.x * blockDim.x + threadIdx.x;
  if (e >= et) return;
  int mode = modep[0];
  int src, dst;
  if (e < e0) { src = load_edge(ei, mode, e); dst = load_edge(ei, mode, e0 + e); }
  else        { src = dst = e - e0; }
  src = clampi(src, 0, NNODES - 1);
  dst = clampi(dst, 0, NNODES - 1);
  int pos = atomicAdd(&cursor[dst], 1);
  col[pos] = src;
}

// ------------------------------ MFMA GEMM ----------------------------------
// C[M,NC] = A[M,K] @ W[K,NC]; A bf16 [M][K], Wt bf16 [NC][K]; C bf16.
// Tile 64x64, BK=32, 4 waves; mfma_f32_16x16x32_bf16.

template <int K, int NC>
__global__ __launch_bounds__(256) void gemm_mfma_kernel(const bf16_t* __restrict__ A,
                                                        const bf16_t* __restrict__ Wt,
                                                        bf16_t* __restrict__ C, int M) {
  __shared__ __align__(16) ushort As[64 * 40];
  __shared__ __align__(16) ushort Bs[64 * 40];
  const int t    = threadIdx.x;
  const int wv   = t >> 6;
  const int lane = t & 63;
  const int m    = lane & 15;
  const int quad = lane >> 4;
  const int bm = blockIdx.x * 64, bn = blockIdx.y * 64;

  const int srow = t & 63;
  const int sk8  = t >> 6;

  f32x4 acc0 = {0.f, 0.f, 0.f, 0.f};
  f32x4 acc1 = {0.f, 0.f, 0.f, 0.f};
  f32x4 acc2 = {0.f, 0.f, 0.f, 0.f};
  f32x4 acc3 = {0.f, 0.f, 0.f, 0.f};

  for (int k0 = 0; k0 < K; k0 += 32) {
    int ga = clampi(bm + srow, 0, M - 1);
    float4 av = *(const float4*)(A + (size_t)ga * K + k0 + sk8 * 8);
    *(float4*)(&As[srow * 40 + sk8 * 8]) = av;
    float4 bv = *(const float4*)(Wt + (size_t)(bn + srow) * K + k0 + sk8 * 8);
    *(float4*)(&Bs[srow * 40 + sk8 * 8]) = bv;
    __syncthreads();

    bf16x8 af = *(const bf16x8*)(&As[(wv * 16 + m) * 40 + quad * 8]);
    bf16x8 b0 = *(const bf16x8*)(&Bs[(0 * 16 + m) * 40 + quad * 8]);
    bf16x8 b1 = *(const bf16x8*)(&Bs[(1 * 16 + m) * 40 + quad * 8]);
    bf16x8 b2 = *(const bf16x8*)(&Bs[(2 * 16 + m) * 40 + quad * 8]);
    bf16x8 b3 = *(const bf16x8*)(&Bs[(3 * 16 + m) * 40 + quad * 8]);
    acc0 = __builtin_amdgcn_mfma_f32_16x16x32_bf16(af, b0, acc0, 0, 0, 0);
    acc1 = __builtin_amdgcn_mfma_f32_16x16x32_bf16(af, b1, acc1, 0, 0, 0);
    acc2 = __builtin_amdgcn_mfma_f32_16x16x32_bf16(af, b2, acc2, 0, 0, 0);
    acc3 = __builtin_amdgcn_mfma_f32_16x16x32_bf16(af, b3, acc3, 0, 0, 0);
    __syncthreads();
  }

#pragma unroll
  for (int r = 0; r < 4; ++r) {
    int row = bm + wv * 16 + quad * 4 + r;
    if (row < M) {
      size_t base = (size_t)row * NC + bn;
      C[base +  0 + m] = f2bf(acc0[r]);
      C[base + 16 + m] = f2bf(acc1[r]);
      C[base + 32 + m] = f2bf(acc2[r]);
      C[base + 48 + m] = f2bf(acc3[r]);
    }
  }
}

// ------------------------------ attention scores ---------------------------
__global__ __launch_bounds__(256) void scores1_kernel(const bf16_t* __restrict__ h,
                                                      const float* __restrict__ asrc,
                                                      const float* __restrict__ adst,
                                                      float* __restrict__ es,
                                                      float* __restrict__ ed) {
  int node = (blockIdx.x * blockDim.x + threadIdx.x) >> 6;
  if (node >= NNODES) return;
  int lane = threadIdx.x & 63;
  float4 hv = bf4_to_f4(*(const ushort4*)(h + (size_t)node * 256 + 4 * lane));
  float4 av = *(const float4*)(asrc + 4 * lane);
  float4 dv = *(const float4*)(adst + 4 * lane);
  float ps = hv.x * av.x + hv.y * av.y + hv.z * av.z + hv.w * av.w;
  float pd = hv.x * dv.x + hv.y * dv.y + hv.z * dv.z + hv.w * dv.w;
  for (int m = 1; m < 16; m <<= 1) { ps += __shfl_xor(ps, m); pd += __shfl_xor(pd, m); }
  if ((lane & 15) == 0) {
    es[node * 4 + (lane >> 4)] = ps;
    ed[node * 4 + (lane >> 4)] = pd;
  }
}

__global__ __launch_bounds__(256) void scores2_kernel(const bf16_t* __restrict__ h,
                                                      const float* __restrict__ asrc,
                                                      const float* __restrict__ adst,
                                                      float* __restrict__ es,
                                                      float* __restrict__ ed) {
  int node = (blockIdx.x * blockDim.x + threadIdx.x) >> 6;
  if (node >= NNODES) return;
  int lane = threadIdx.x & 63;
  float4 hA = bf4_to_f4(*(const ushort4*)(h + (size_t)node * 512 + 4 * lane));
  float4 hB = bf4_to_f4(*(const ushort4*)(h + (size_t)node * 512 + 4 * lane + 256));
  float4 aA = *(const float4*)(asrc + 4 * lane);
  float4 aB = *(const float4*)(asrc + 4 * lane + 256);
  float4 dA = *(const float4*)(adst + 4 * lane);
  float4 dB = *(const float4*)(adst + 4 * lane + 256);
  float psA = hA.x * aA.x + hA.y * aA.y + hA.z * aA.z + hA.w * aA.w;
  float psB = hB.x * aB.x + hB.y * aB.y + hB.z * aB.z + hB.w * aB.w;
  float pdA = hA.x * dA.x + hA.y * dA.y + hA.z * dA.z + hA.w * dA.w;
  float pdB = hB.x * dB.x + hB.y * dB.y + hB.z * dB.z + hB.w * dB.w;
  for (int m = 1; m < 32; m <<= 1) {
    psA += __shfl_xor(psA, m); psB += __shfl_xor(psB, m);
    pdA += __shfl_xor(pdA, m); pdB += __shfl_xor(pdB, m);
  }
  if ((lane & 31) == 0) {
    int g = lane >> 5;
    es[node * 4 + g]     = psA;  es[node * 4 + g + 2] = psB;
    ed[node * 4 + g]     = pdA;  ed[node * 4 + g + 2] = pdB;
  }
}

// --------------------------- softmax prep (alpha) --------------------------
// wave per node; lanes edge-parallel. 3 loops over the node's edge list:
// max, sum-exp, write alpha4[p] = exp(e-m)/(l+1e-16).  es is L2-resident.
__global__ __launch_bounds__(256) void softmax_prep_kernel(
    const float* __restrict__ es, const float* __restrict__ ed,
    const int* __restrict__ rowptr, const int* __restrict__ col,
    float* __restrict__ alpha) {
  int node = (blockIdx.x * blockDim.x + threadIdx.x) >> 6;
  if (node >= NNODES) return;
  int lane = threadIdx.x & 63;
  int beg = rowptr[node], end = rowptr[node + 1];
  float4 edv = *(const float4*)(ed + node * 4);
  float ninf = -__builtin_inff();
  float4 m = make_float4(ninf, ninf, ninf, ninf);
  for (int p = beg + lane; p < end; p += 64) {
    int s = col[p];
    float4 e = *(const float4*)(es + s * 4);
    m.x = fmaxf(m.x, lrelu(e.x + edv.x));
    m.y = fmaxf(m.y, lrelu(e.y + edv.y));
    m.z = fmaxf(m.z, lrelu(e.z + edv.z));
    m.w = fmaxf(m.w, lrelu(e.w + edv.w));
  }
  for (int off = 1; off < 64; off <<= 1) {
    m.x = fmaxf(m.x, __shfl_xor(m.x, off));
    m.y = fmaxf(m.y, __shfl_xor(m.y, off));
    m.z = fmaxf(m.z, __shfl_xor(m.z, off));
    m.w = fmaxf(m.w, __shfl_xor(m.w, off));
  }
  float4 l = make_float4(0.f, 0.f, 0.f, 0.f);
  for (int p = beg + lane; p < end; p += 64) {
    int s = col[p];
    float4 e = *(const float4*)(es + s * 4);
    l.x += __expf(lrelu(e.x + edv.x) - m.x);
    l.y += __expf(lrelu(e.y + edv.y) - m.y);
    l.z += __expf(lrelu(e.z + edv.z) - m.z);
    l.w += __expf(lrelu(e.w + edv.w) - m.w);
  }
  for (int off = 1; off < 64; off <<= 1) {
    l.x += __shfl_xor(l.x, off);
    l.y += __shfl_xor(l.y, off);
    l.z += __shfl_xor(l.z, off);
    l.w += __shfl_xor(l.w, off);
  }
  float4 il = make_float4(1.f / (l.x + 1e-16f), 1.f / (l.y + 1e-16f),
                          1.f / (l.z + 1e-16f), 1.f / (l.w + 1e-16f));
  for (int p = beg + lane; p < end; p += 64) {
    int s = col[p];
    float4 e = *(const float4*)(es + s * 4);
    float4 a;
    a.x = __expf(lrelu(e.x + edv.x) - m.x) * il.x;
    a.y = __expf(lrelu(e.y + edv.y) - m.y) * il.y;
    a.z = __expf(lrelu(e.z + edv.z) - m.z) * il.z;
    a.w = __expf(lrelu(e.w + edv.w) - m.w) * il.w;
    *(float4*)(alpha + (size_t)p * 4) = a;
  }
}

// ------------------------------- aggregation -------------------------------
// layer 1: wave per node; lane holds 4 channels at 4*lane (head = lane>>4).
// Pure weighted gather: acc += alpha * h[src].
__global__ __launch_bounds__(256) void aggregate1_kernel(
    const bf16_t* __restrict__ h, const float* __restrict__ alpha,
    const int* __restrict__ rowptr, const int* __restrict__ col,
    const float* __restrict__ b1, bf16_t* __restrict__ out) {
  int node = (blockIdx.x * blockDim.x + threadIdx.x) >> 6;
  if (node >= NNODES) return;
  int lane = threadIdx.x & 63;
  int head = lane >> 4;
  int beg = rowptr[node], end = rowptr[node + 1];
  const ushort4* hb = (const ushort4*)h;   // row = 64 ushort4
  float4 acc = make_float4(0.f, 0.f, 0.f, 0.f);
  for (int j = beg; j < end; ++j) {
    int s = col[j];
    float a = alpha[(size_t)j * 4 + head];
    float4 hv = bf4_to_f4(hb[(size_t)s * 64 + lane]);
    acc.x += a * hv.x;
    acc.y += a * hv.y;
    acc.z += a * hv.z;
    acc.w += a * hv.w;
  }
  float4 bb = *(const float4*)(b1 + 4 * lane);
  float4 o;
  o.x = fmaxf(acc.x + bb.x, 0.f);
  o.y = fmaxf(acc.y + bb.y, 0.f);
  o.z = fmaxf(acc.z + bb.z, 0.f);
  o.w = fmaxf(acc.w + bb.w, 0.f);
  *(ushort4*)(out + (size_t)node * 256 + 4 * lane) = f4_to_bf4(o);
}

// layer 2: wave per node; lane holds chunks at 4*lane (head hA=lane>>5) and
// 4*lane+256 (head hB=hA+2). Epilogue: head mean, +b2, LayerNorm, fp32 out.
__global__ __launch_bounds__(256) void aggregate2_ln_kernel(
    const bf16_t* __restrict__ h, const float* __restrict__ alpha,
    const int* __restrict__ rowptr, const int* __restrict__ col,
    const float* __restrict__ b2, const float* __restrict__ gamma,
    const float* __restrict__ beta, float* __restrict__ out) {
  int node = (blockIdx.x * blockDim.x + threadIdx.x) >> 6;
  if (node >= NNODES) return;
  int lane = threadIdx.x & 63;
  int hA = lane >> 5, hB = hA + 2;
  int beg = rowptr[node], end = rowptr[node + 1];
  const ushort4* hb = (const ushort4*)h;   // row = 128 ushort4
  float4 accA = make_float4(0.f, 0.f, 0.f, 0.f);
  float4 accB = make_float4(0.f, 0.f, 0.f, 0.f);
  for (int j = beg; j < end; ++j) {
    int s = col[j];
    float aA = alpha[(size_t)j * 4 + hA];
    float aB = alpha[(size_t)j * 4 + hB];
    float4 vA = bf4_to_f4(hb[(size_t)s * 128 + lane]);
    float4 vB = bf4_to_f4(hb[(size_t)s * 128 + lane + 64]);
    accA.x += aA * vA.x;
    accA.y += aA * vA.y;
    accA.z += aA * vA.z;
    accA.w += aA * vA.w;
    accB.x += aB * vB.x;
    accB.y += aB * vB.y;
    accB.z += aB * vB.z;
    accB.w += aB * vB.w;
  }
  float4 s4;
  s4.x = accA.x + accB.x;
  s4.y = accA.y + accB.y;
  s4.z = accA.z + accB.z;
  s4.w = accA.w + accB.w;
  s4.x += __shfl_xor(s4.x, 32);
  s4.y += __shfl_xor(s4.y, 32);
  s4.z += __shfl_xor(s4.z, 32);
  s4.w += __shfl_xor(s4.w, 32);
  int c0 = (4 * lane) & 127;
  float4 b2v = *(const float4*)(b2 + c0);
  s4.x = s4.x * 0.25f + b2v.x;
  s4.y = s4.y * 0.25f + b2v.y;
  s4.z = s4.z * 0.25f + b2v.z;
  s4.w = s4.w * 0.25f + b2v.w;
  float part = s4.x + s4.y + s4.z + s4.w;
  for (int m = 1; m < 32; m <<= 1) part += __shfl_xor(part, m);
  float mu = part * (1.f / 128.f);
  float dx = s4.x - mu, dy = s4.y - mu, dz = s4.z - mu, dw = s4.w - mu;
  float sq = dx * dx + dy * dy + dz * dz + dw * dw;
  for (int m = 1; m < 32; m <<= 1) sq += __shfl_xor(sq, m);
  float r = rsqrtf(sq * (1.f / 128.f) + 1e-5f);
  float4 g = *(const float4*)(gamma + c0);
  float4 bt = *(const float4*)(beta + c0);
  if (lane < 32) {
    float4 o;
    o.x = dx * r * g.x + bt.x;
    o.y = dy * r * g.y + bt.y;
    o.z = dz * r * g.z + bt.z;
    o.w = dw * r * g.w + bt.w;
    *(float4*)(out + (size_t)node * 128 + c0) = o;
  }
}

// ------------------------------- launcher ----------------------------------

extern "C" void kernel_launch(void* const* d_in, const int* in_sizes, int n_in,
                              void* d_out, int out_size, void* d_ws, size_t ws_size,
                              hipStream_t stream) {
  const float* x     = (const float*)d_in[0];
  const void*  ei    = d_in[1];
  const float* W1    = (const float*)d_in[2];
  const float* asrc1 = (const float*)d_in[3];
  const float* adst1 = (const float*)d_in[4];
  const float* b1    = (const float*)d_in[5];
  const float* W2    = (const float*)d_in[6];
  const float* asrc2 = (const float*)d_in[7];
  const float* adst2 = (const float*)d_in[8];
  const float* b2    = (const float*)d_in[9];
  const float* gamma = (const float*)d_in[10];
  const float* beta  = (const float*)d_in[11];
  float* out = (float*)d_out;

  const int E0 = in_sizes[1] / 2;       // 800000 raw edges
  const int ET = E0 + NNODES;           // + self loops

  // ws layout (< 90 MB, proven-safe by R6 guard). Overlays by lifetime:
  //   alpha1 [0,13.6M)        prep1..agg1   (h2 not yet written)
  //   h2     [0,51.2M)        gemm2..agg2
  //   h1     [25.6M,51.2M)    gemm1..agg1   (inside h2's future region)
  //   xb     [51.2M,64M)      conv..gemm1
  //   out1   [51.2M,76.8M)    agg1..gemm2
  //   alpha2 [51.2M,64.8M)    prep2..agg2   (out1 dead after gemm2)
  char* w = (char*)d_ws;
  float*  alpha1 = (float*)(w + 0);
  bf16_t* h2     = (bf16_t*)(w + 0);
  bf16_t* h1     = (bf16_t*)(w + 25600000);
  bf16_t* xb     = (bf16_t*)(w + 51200000);
  bf16_t* out1   = (bf16_t*)(w + 51200000);
  float*  alpha2 = (float*)(w + 51200000);
  bf16_t* Wt1    = (bf16_t*)(w + 76800000);
  bf16_t* Wt2    = (bf16_t*)(w + 76870000);
  float* es1  = (float*)(w + 77200000);
  float* ed1  = (float*)(w + 78000000);
  float* es2  = (float*)(w + 78800000);
  float* ed2  = (float*)(w + 79600000);
  int* rowptr = (int*)(w + 80400000);
  int* cursor = (int*)(w + 80600064);
  int* counts = (int*)(w + 80800128);
  int* col    = (int*)(w + 81000192);
  int* bsums  = (int*)(w + 84400192);
  int* boff   = (int*)(w + 84400448);
  int* mode   = (int*)(w + 84400704);

  const int NB = (NNODES + 1023) / 1024;   // 49

  // ---- prep: bf16 conversions ----
  convert_x_kernel<<<(NNODES * 128 / 4 + 255) / 256, 256, 0, stream>>>(x, xb,
                                                                       NNODES * 128 / 4);
  transpose_w_kernel<128, 256><<<256, 128, 0, stream>>>(W1, Wt1);
  transpose_w_kernel<256, 512><<<512, 256, 0, stream>>>(W2, Wt2);

  // ---- edge dtype detect + CSR build ----
  detect_kernel<<<1, 256, 0, stream>>>((const int*)ei, mode);
  zero_kernel<<<(NNODES + 255) / 256, 256, 0, stream>>>(counts, NNODES);
  hist_kernel<<<(ET + 255) / 256, 256, 0, stream>>>(ei, mode, counts, E0, ET);
  scan1_kernel<<<NB, 1024, 0, stream>>>(counts, rowptr, bsums);
  scan2_kernel<<<1, 64, 0, stream>>>(bsums, boff, NB, rowptr, cursor);
  scan3_kernel<<<NB, 1024, 0, stream>>>(boff, rowptr, cursor);
  fill_kernel<<<(ET + 255) / 256, 256, 0, stream>>>(ei, mode, cursor, col, E0, ET);

  const int MB = (NNODES + 63) / 64;       // 782
  const int NODE_BLOCKS = (NNODES + 3) / 4;

  // ---- layer 1 ----
  gemm_mfma_kernel<128, 256><<<dim3(MB, 4), 256, 0, stream>>>(xb, Wt1, h1, NNODES);
  scores1_kernel<<<NODE_BLOCKS, 256, 0, stream>>>(h1, asrc1, adst1, es1, ed1);
  softmax_prep_kernel<<<NODE_BLOCKS, 256, 0, stream>>>(es1, ed1, rowptr, col, alpha1);
  aggregate1_kernel<<<NODE_BLOCKS, 256, 0, stream>>>(h1, alpha1, rowptr, col, b1, out1);

  // ---- layer 2 ----
  gemm_mfma_kernel<256, 512><<<dim3(MB, 8), 256, 0, stream>>>(out1, Wt2, h2, NNODES);
  scores2_kernel<<<NODE_BLOCKS, 256, 0, stream>>>(h2, asrc2, adst2, es2, ed2);
  softmax_prep_kernel<<<NODE_BLOCKS, 256, 0, stream>>>(es2, ed2, rowptr, col, alpha2);
  aggregate2_ln_kernel<<<NODE_BLOCKS, 256, 0, stream>>>(h2, alpha2, rowptr, col,
                                                        b2, gamma, beta, out);
}

// Round 10
// 564.942 us; speedup vs baseline: 1.0561x; 1.0561x over previous
//
#include <hip/hip_runtime.h>
#include <cstdint>
#include <cstddef>

// ---------------------------------------------------------------------------
// GAT x2 + LayerNorm on MI355X.
// Interface (established R0-R7): inputs fp32, edge_index int32, output fp32.
// R8: MFMA bf16 GEMMs. R10: per-node softmax stats (m, 1/l) + inline alpha in
// aggregates; gather loop unrolled x2 for memory-level parallelism.
// ---------------------------------------------------------------------------

constexpr int NNODES = 50000;

typedef unsigned short bf16_t;
typedef __attribute__((ext_vector_type(8))) short bf16x8;
typedef __attribute__((ext_vector_type(4))) float f32x4;

__device__ __forceinline__ float bf2f(bf16_t b) {
  return __uint_as_float(((unsigned int)b) << 16);
}
__device__ __forceinline__ bf16_t f2bf(float f) {
  unsigned int u = __float_as_uint(f);
  u += 0x7fffu + ((u >> 16) & 1u);   // round to nearest even
  return (bf16_t)(u >> 16);
}
__device__ __forceinline__ float4 bf4_to_f4(ushort4 v) {
  return make_float4(bf2f(v.x), bf2f(v.y), bf2f(v.z), bf2f(v.w));
}
__device__ __forceinline__ ushort4 f4_to_bf4(float4 v) {
  return make_ushort4(f2bf(v.x), f2bf(v.y), f2bf(v.z), f2bf(v.w));
}
__device__ __forceinline__ float lrelu(float x) { return x > 0.f ? x : 0.2f * x; }
__device__ __forceinline__ int clampi(int v, int lo, int hi) {
  return v < lo ? lo : (v > hi ? hi : v);
}
__device__ __forceinline__ int load_edge(const void* ei, int mode, int idx) {
  if (mode) return (int)((const long long*)ei)[idx];
  return ((const int*)ei)[idx];
}

// ------------------------------ prep kernels -------------------------------

__global__ void convert_x_kernel(const float* __restrict__ x, bf16_t* __restrict__ xb,
                                 int n4) {
  int i = blockIdx.x * blockDim.x + threadIdx.x;
  if (i >= n4) return;
  float4 v = *(const float4*)(x + 4 * (size_t)i);
  *(ushort4*)(xb + 4 * (size_t)i) = f4_to_bf4(v);
}

// Wt[n][k] = bf16(W[k][n]);  grid = NC blocks, block = K threads
template <int K, int NC>
__global__ void transpose_w_kernel(const float* __restrict__ W, bf16_t* __restrict__ Wt) {
  int n = blockIdx.x;
  int k = threadIdx.x;
  Wt[(size_t)n * K + k] = f2bf(W[(size_t)k * NC + n]);
}

// --------------------------- edge dtype detection --------------------------
__global__ void detect_kernel(const int* __restrict__ ei32, int* __restrict__ mode) {
  __shared__ int nz;
  if (threadIdx.x == 0) nz = 0;
  __syncthreads();
  int idx = 2 * threadIdx.x + 1;
  if (ei32[idx] != 0) atomicAdd(&nz, 1);
  __syncthreads();
  if (threadIdx.x == 0) mode[0] = (nz == 0) ? 1 : 0;
}

// ------------------------------- CSR build ---------------------------------

__global__ void zero_kernel(int* __restrict__ p, int n) {
  int i = blockIdx.x * blockDim.x + threadIdx.x;
  if (i < n) p[i] = 0;
}

__global__ void hist_kernel(const void* __restrict__ ei, const int* __restrict__ modep,
                            int* __restrict__ counts, int e0, int et) {
  int e = blockIdx.x * blockDim.x + threadIdx.x;
  if (e >= et) return;
  int mode = modep[0];
  int dst = (e < e0) ? load_edge(ei, mode, e0 + e) : (e - e0);
  dst = clampi(dst, 0, NNODES - 1);
  atomicAdd(&counts[dst], 1);
}

__global__ __launch_bounds__(1024) void scan1_kernel(const int* __restrict__ counts,
                                                     int* __restrict__ rowptr,
                                                     int* __restrict__ bsums) {
  __shared__ int sm[1024];
  int t = threadIdx.x;
  int i = blockIdx.x * 1024 + t;
  sm[t] = (i < NNODES) ? counts[i] : 0;
  __syncthreads();
  for (int off = 1; off < 1024; off <<= 1) {
    int u = (t >= off) ? sm[t - off] : 0;
    __syncthreads();
    sm[t] += u;
    __syncthreads();
  }
  if (i < NNODES) rowptr[i + 1] = sm[t];
  if (t == 1023) bsums[blockIdx.x] = sm[1023];
}

__global__ void scan2_kernel(const int* __restrict__ bsums, int* __restrict__ boff,
                             int nb, int* __restrict__ rowptr, int* __restrict__ cursor) {
  if (threadIdx.x == 0 && blockIdx.x == 0) {
    int run = 0;
    for (int b = 0; b < nb; ++b) { boff[b] = run; run += bsums[b]; }
    rowptr[0] = 0;
    cursor[0] = 0;
  }
}

__global__ __launch_bounds__(1024) void scan3_kernel(const int* __restrict__ boff,
                                                     int* __restrict__ rowptr,
                                                     int* __restrict__ cursor) {
  int i = blockIdx.x * 1024 + threadIdx.x;
  if (i < NNODES) {
    int v = rowptr[i + 1] + boff[blockIdx.x];
    rowptr[i + 1] = v;
    cursor[i + 1] = v;
  }
}

__global__ void fill_kernel(const void* __restrict__ ei, const int* __restrict__ modep,
                            int* __restrict__ cursor, int* __restrict__ col,
                            int e0, int et) {
  int e = blockIdx.x * blockDim.x + threadIdx.x;
  if (e >= et) return;
  int mode = modep[0];
  int src, dst;
  if (e < e0) { src = load_edge(ei, mode, e); dst = load_edge(ei, mode, e0 + e); }
  else        { src = dst = e - e0; }
  src = clampi(src, 0, NNODES - 1);
  dst = clampi(dst, 0, NNODES - 1);
  int pos = atomicAdd(&cursor[dst], 1);
  col[pos] = src;
}

// ------------------------------ MFMA GEMM ----------------------------------
// C[M,NC] = A[M,K] @ W[K,NC]; A bf16 [M][K], Wt bf16 [NC][K]; C bf16.
// Tile 64x64, BK=32, 4 waves; mfma_f32_16x16x32_bf16.

template <int K, int NC>
__global__ __launch_bounds__(256) void gemm_mfma_kernel(const bf16_t* __restrict__ A,
                                                        const bf16_t* __restrict__ Wt,
                                                        bf16_t* __restrict__ C, int M) {
  __shared__ __align__(16) ushort As[64 * 40];
  __shared__ __align__(16) ushort Bs[64 * 40];
  const int t    = threadIdx.x;
  const int wv   = t >> 6;
  const int lane = t & 63;
  const int m    = lane & 15;
  const int quad = lane >> 4;
  const int bm = blockIdx.x * 64, bn = blockIdx.y * 64;

  const int srow = t & 63;
  const int sk8  = t >> 6;

  f32x4 acc0 = {0.f, 0.f, 0.f, 0.f};
  f32x4 acc1 = {0.f, 0.f, 0.f, 0.f};
  f32x4 acc2 = {0.f, 0.f, 0.f, 0.f};
  f32x4 acc3 = {0.f, 0.f, 0.f, 0.f};

  for (int k0 = 0; k0 < K; k0 += 32) {
    int ga = clampi(bm + srow, 0, M - 1);
    float4 av = *(const float4*)(A + (size_t)ga * K + k0 + sk8 * 8);
    *(float4*)(&As[srow * 40 + sk8 * 8]) = av;
    float4 bv = *(const float4*)(Wt + (size_t)(bn + srow) * K + k0 + sk8 * 8);
    *(float4*)(&Bs[srow * 40 + sk8 * 8]) = bv;
    __syncthreads();

    bf16x8 af = *(const bf16x8*)(&As[(wv * 16 + m) * 40 + quad * 8]);
    bf16x8 b0 = *(const bf16x8*)(&Bs[(0 * 16 + m) * 40 + quad * 8]);
    bf16x8 b1 = *(const bf16x8*)(&Bs[(1 * 16 + m) * 40 + quad * 8]);
    bf16x8 b2 = *(const bf16x8*)(&Bs[(2 * 16 + m) * 40 + quad * 8]);
    bf16x8 b3 = *(const bf16x8*)(&Bs[(3 * 16 + m) * 40 + quad * 8]);
    acc0 = __builtin_amdgcn_mfma_f32_16x16x32_bf16(af, b0, acc0, 0, 0, 0);
    acc1 = __builtin_amdgcn_mfma_f32_16x16x32_bf16(af, b1, acc1, 0, 0, 0);
    acc2 = __builtin_amdgcn_mfma_f32_16x16x32_bf16(af, b2, acc2, 0, 0, 0);
    acc3 = __builtin_amdgcn_mfma_f32_16x16x32_bf16(af, b3, acc3, 0, 0, 0);
    __syncthreads();
  }

#pragma unroll
  for (int r = 0; r < 4; ++r) {
    int row = bm + wv * 16 + quad * 4 + r;
    if (row < M) {
      size_t base = (size_t)row * NC + bn;
      C[base +  0 + m] = f2bf(acc0[r]);
      C[base + 16 + m] = f2bf(acc1[r]);
      C[base + 32 + m] = f2bf(acc2[r]);
      C[base + 48 + m] = f2bf(acc3[r]);
    }
  }
}

// ------------------------------ attention scores ---------------------------
__global__ __launch_bounds__(256) void scores1_kernel(const bf16_t* __restrict__ h,
                                                      const float* __restrict__ asrc,
                                                      const float* __restrict__ adst,
                                                      float* __restrict__ es,
                                                      float* __restrict__ ed) {
  int node = (blockIdx.x * blockDim.x + threadIdx.x) >> 6;
  if (node >= NNODES) return;
  int lane = threadIdx.x & 63;
  float4 hv = bf4_to_f4(*(const ushort4*)(h + (size_t)node * 256 + 4 * lane));
  float4 av = *(const float4*)(asrc + 4 * lane);
  float4 dv = *(const float4*)(adst + 4 * lane);
  float ps = hv.x * av.x + hv.y * av.y + hv.z * av.z + hv.w * av.w;
  float pd = hv.x * dv.x + hv.y * dv.y + hv.z * dv.z + hv.w * dv.w;
  for (int m = 1; m < 16; m <<= 1) { ps += __shfl_xor(ps, m); pd += __shfl_xor(pd, m); }
  if ((lane & 15) == 0) {
    es[node * 4 + (lane >> 4)] = ps;
    ed[node * 4 + (lane >> 4)] = pd;
  }
}

__global__ __launch_bounds__(256) void scores2_kernel(const bf16_t* __restrict__ h,
                                                      const float* __restrict__ asrc,
                                                      const float* __restrict__ adst,
                                                      float* __restrict__ es,
                                                      float* __restrict__ ed) {
  int node = (blockIdx.x * blockDim.x + threadIdx.x) >> 6;
  if (node >= NNODES) return;
  int lane = threadIdx.x & 63;
  float4 hA = bf4_to_f4(*(const ushort4*)(h + (size_t)node * 512 + 4 * lane));
  float4 hB = bf4_to_f4(*(const ushort4*)(h + (size_t)node * 512 + 4 * lane + 256));
  float4 aA = *(const float4*)(asrc + 4 * lane);
  float4 aB = *(const float4*)(asrc + 4 * lane + 256);
  float4 dA = *(const float4*)(adst + 4 * lane);
  float4 dB = *(const float4*)(adst + 4 * lane + 256);
  float psA = hA.x * aA.x + hA.y * aA.y + hA.z * aA.z + hA.w * aA.w;
  float psB = hB.x * aB.x + hB.y * aB.y + hB.z * aB.z + hB.w * aB.w;
  float pdA = hA.x * dA.x + hA.y * dA.y + hA.z * dA.z + hA.w * dA.w;
  float pdB = hB.x * dB.x + hB.y * dB.y + hB.z * dB.z + hB.w * dB.w;
  for (int m = 1; m < 32; m <<= 1) {
    psA += __shfl_xor(psA, m); psB += __shfl_xor(psB, m);
    pdA += __shfl_xor(pdA, m); pdB += __shfl_xor(pdB, m);
  }
  if ((lane & 31) == 0) {
    int g = lane >> 5;
    es[node * 4 + g]     = psA;  es[node * 4 + g + 2] = psB;
    ed[node * 4 + g]     = pdA;  ed[node * 4 + g + 2] = pdB;
  }
}

// --------------------------- softmax stats (m, 1/l) ------------------------
// wave per node; lanes edge-parallel; 2 passes over edge list; writes
// m4[node], il4[node].  es is L2-resident (800 KB).
__global__ __launch_bounds__(256) void stats_kernel(
    const float* __restrict__ es, const float* __restrict__ ed,
    const int* __restrict__ rowptr, const int* __restrict__ col,
    float* __restrict__ m_out, float* __restrict__ il_out) {
  int node = (blockIdx.x * blockDim.x + threadIdx.x) >> 6;
  if (node >= NNODES) return;
  int lane = threadIdx.x & 63;
  int beg = rowptr[node], end = rowptr[node + 1];
  float4 edv = *(const float4*)(ed + node * 4);
  float ninf = -__builtin_inff();
  float4 m = make_float4(ninf, ninf, ninf, ninf);
  for (int p = beg + lane; p < end; p += 64) {
    int s = col[p];
    float4 e = *(const float4*)(es + s * 4);
    m.x = fmaxf(m.x, lrelu(e.x + edv.x));
    m.y = fmaxf(m.y, lrelu(e.y + edv.y));
    m.z = fmaxf(m.z, lrelu(e.z + edv.z));
    m.w = fmaxf(m.w, lrelu(e.w + edv.w));
  }
  for (int off = 1; off < 64; off <<= 1) {
    m.x = fmaxf(m.x, __shfl_xor(m.x, off));
    m.y = fmaxf(m.y, __shfl_xor(m.y, off));
    m.z = fmaxf(m.z, __shfl_xor(m.z, off));
    m.w = fmaxf(m.w, __shfl_xor(m.w, off));
  }
  float4 l = make_float4(0.f, 0.f, 0.f, 0.f);
  for (int p = beg + lane; p < end; p += 64) {
    int s = col[p];
    float4 e = *(const float4*)(es + s * 4);
    l.x += __expf(lrelu(e.x + edv.x) - m.x);
    l.y += __expf(lrelu(e.y + edv.y) - m.y);
    l.z += __expf(lrelu(e.z + edv.z) - m.z);
    l.w += __expf(lrelu(e.w + edv.w) - m.w);
  }
  for (int off = 1; off < 64; off <<= 1) {
    l.x += __shfl_xor(l.x, off);
    l.y += __shfl_xor(l.y, off);
    l.z += __shfl_xor(l.z, off);
    l.w += __shfl_xor(l.w, off);
  }
  if (lane == 0) {
    *(float4*)(m_out + node * 4) = m;
    float4 il = make_float4(1.f / (l.x + 1e-16f), 1.f / (l.y + 1e-16f),
                            1.f / (l.z + 1e-16f), 1.f / (l.w + 1e-16f));
    *(float4*)(il_out + node * 4) = il;
  }
}

// ------------------------------- aggregation -------------------------------
// layer 1: wave per node; lane holds 4 channels at 4*lane (head = lane>>4).
// alpha computed inline: a = exp(lrelu(es+ed) - m) * il.  Unrolled x2.
__global__ __launch_bounds__(256) void aggregate1_kernel(
    const bf16_t* __restrict__ h, const float* __restrict__ es,
    const float* __restrict__ ed, const float* __restrict__ ms,
    const float* __restrict__ ils, const int* __restrict__ rowptr,
    const int* __restrict__ col, const float* __restrict__ b1,
    bf16_t* __restrict__ out) {
  int node = (blockIdx.x * blockDim.x + threadIdx.x) >> 6;
  if (node >= NNODES) return;
  int lane = threadIdx.x & 63;
  int head = lane >> 4;
  float edv = ed[node * 4 + head];
  float mv  = ms[node * 4 + head];
  float ilv = ils[node * 4 + head];
  int beg = rowptr[node], end = rowptr[node + 1];
  const ushort4* hb = (const ushort4*)h;   // row = 64 ushort4
  float4 acc = make_float4(0.f, 0.f, 0.f, 0.f);
  int j = beg;
  for (; j + 2 <= end; j += 2) {
    int s0 = col[j], s1 = col[j + 1];
    float e0 = es[s0 * 4 + head];
    float e1 = es[s1 * 4 + head];
    ushort4 r0 = hb[(size_t)s0 * 64 + lane];
    ushort4 r1 = hb[(size_t)s1 * 64 + lane];
    float a0 = __expf(lrelu(e0 + edv) - mv) * ilv;
    float a1 = __expf(lrelu(e1 + edv) - mv) * ilv;
    float4 v0 = bf4_to_f4(r0);
    float4 v1 = bf4_to_f4(r1);
    acc.x += a0 * v0.x + a1 * v1.x;
    acc.y += a0 * v0.y + a1 * v1.y;
    acc.z += a0 * v0.z + a1 * v1.z;
    acc.w += a0 * v0.w + a1 * v1.w;
  }
  if (j < end) {
    int s0 = col[j];
    float e0 = es[s0 * 4 + head];
    float a0 = __expf(lrelu(e0 + edv) - mv) * ilv;
    float4 v0 = bf4_to_f4(hb[(size_t)s0 * 64 + lane]);
    acc.x += a0 * v0.x;
    acc.y += a0 * v0.y;
    acc.z += a0 * v0.z;
    acc.w += a0 * v0.w;
  }
  float4 bb = *(const float4*)(b1 + 4 * lane);
  float4 o;
  o.x = fmaxf(acc.x + bb.x, 0.f);
  o.y = fmaxf(acc.y + bb.y, 0.f);
  o.z = fmaxf(acc.z + bb.z, 0.f);
  o.w = fmaxf(acc.w + bb.w, 0.f);
  *(ushort4*)(out + (size_t)node * 256 + 4 * lane) = f4_to_bf4(o);
}

// layer 2: wave per node; chunks at 4*lane (head hA=lane>>5) and +256
// (head hB=hA+2). Inline alpha, unrolled x2. Epilogue: head-mean, +b2,
// LayerNorm over 128, fp32 store.
__global__ __launch_bounds__(256) void aggregate2_ln_kernel(
    const bf16_t* __restrict__ h, const float* __restrict__ es,
    const float* __restrict__ ed, const float* __restrict__ ms,
    const float* __restrict__ ils, const int* __restrict__ rowptr,
    const int* __restrict__ col, const float* __restrict__ b2,
    const float* __restrict__ gamma, const float* __restrict__ beta,
    float* __restrict__ out) {
  int node = (blockIdx.x * blockDim.x + threadIdx.x) >> 6;
  if (node >= NNODES) return;
  int lane = threadIdx.x & 63;
  int hA = lane >> 5, hB = hA + 2;
  float edA = ed[node * 4 + hA],  edB = ed[node * 4 + hB];
  float mA  = ms[node * 4 + hA],  mB  = ms[node * 4 + hB];
  float ilA = ils[node * 4 + hA], ilB = ils[node * 4 + hB];
  int beg = rowptr[node], end = rowptr[node + 1];
  const ushort4* hb = (const ushort4*)h;   // row = 128 ushort4
  float4 accA = make_float4(0.f, 0.f, 0.f, 0.f);
  float4 accB = make_float4(0.f, 0.f, 0.f, 0.f);
  int j = beg;
  for (; j + 2 <= end; j += 2) {
    int s0 = col[j], s1 = col[j + 1];
    float eA0 = es[s0 * 4 + hA], eB0 = es[s0 * 4 + hB];
    float eA1 = es[s1 * 4 + hA], eB1 = es[s1 * 4 + hB];
    ushort4 rA0 = hb[(size_t)s0 * 128 + lane];
    ushort4 rB0 = hb[(size_t)s0 * 128 + lane + 64];
    ushort4 rA1 = hb[(size_t)s1 * 128 + lane];
    ushort4 rB1 = hb[(size_t)s1 * 128 + lane + 64];
    float aA0 = __expf(lrelu(eA0 + edA) - mA) * ilA;
    float aB0 = __expf(lrelu(eB0 + edB) - mB) * ilB;
    float aA1 = __expf(lrelu(eA1 + edA) - mA) * ilA;
    float aB1 = __expf(lrelu(eB1 + edB) - mB) * ilB;
    float4 vA0 = bf4_to_f4(rA0), vB0 = bf4_to_f4(rB0);
    float4 vA1 = bf4_to_f4(rA1), vB1 = bf4_to_f4(rB1);
    accA.x += aA0 * vA0.x + aA1 * vA1.x;
    accA.y += aA0 * vA0.y + aA1 * vA1.y;
    accA.z += aA0 * vA0.z + aA1 * vA1.z;
    accA.w += aA0 * vA0.w + aA1 * vA1.w;
    accB.x += aB0 * vB0.x + aB1 * vB1.x;
    accB.y += aB0 * vB0.y + aB1 * vB1.y;
    accB.z += aB0 * vB0.z + aB1 * vB1.z;
    accB.w += aB0 * vB0.w + aB1 * vB1.w;
  }
  if (j < end) {
    int s0 = col[j];
    float eA0 = es[s0 * 4 + hA], eB0 = es[s0 * 4 + hB];
    float aA0 = __expf(lrelu(eA0 + edA) - mA) * ilA;
    float aB0 = __expf(lrelu(eB0 + edB) - mB) * ilB;
    float4 vA0 = bf4_to_f4(hb[(size_t)s0 * 128 + lane]);
    float4 vB0 = bf4_to_f4(hb[(size_t)s0 * 128 + lane + 64]);
    accA.x += aA0 * vA0.x;
    accA.y += aA0 * vA0.y;
    accA.z += aA0 * vA0.z;
    accA.w += aA0 * vA0.w;
    accB.x += aB0 * vB0.x;
    accB.y += aB0 * vB0.y;
    accB.z += aB0 * vB0.z;
    accB.w += aB0 * vB0.w;
  }
  float4 s4;
  s4.x = accA.x + accB.x;
  s4.y = accA.y + accB.y;
  s4.z = accA.z + accB.z;
  s4.w = accA.w + accB.w;
  s4.x += __shfl_xor(s4.x, 32);
  s4.y += __shfl_xor(s4.y, 32);
  s4.z += __shfl_xor(s4.z, 32);
  s4.w += __shfl_xor(s4.w, 32);
  int c0 = (4 * lane) & 127;
  float4 b2v = *(const float4*)(b2 + c0);
  s4.x = s4.x * 0.25f + b2v.x;
  s4.y = s4.y * 0.25f + b2v.y;
  s4.z = s4.z * 0.25f + b2v.z;
  s4.w = s4.w * 0.25f + b2v.w;
  float part = s4.x + s4.y + s4.z + s4.w;
  for (int m = 1; m < 32; m <<= 1) part += __shfl_xor(part, m);
  float mu = part * (1.f / 128.f);
  float dx = s4.x - mu, dy = s4.y - mu, dz = s4.z - mu, dw = s4.w - mu;
  float sq = dx * dx + dy * dy + dz * dz + dw * dw;
  for (int m = 1; m < 32; m <<= 1) sq += __shfl_xor(sq, m);
  float r = rsqrtf(sq * (1.f / 128.f) + 1e-5f);
  float4 g = *(const float4*)(gamma + c0);
  float4 bt = *(const float4*)(beta + c0);
  if (lane < 32) {
    float4 o;
    o.x = dx * r * g.x + bt.x;
    o.y = dy * r * g.y + bt.y;
    o.z = dz * r * g.z + bt.z;
    o.w = dw * r * g.w + bt.w;
    *(float4*)(out + (size_t)node * 128 + c0) = o;
  }
}

// ------------------------------- launcher ----------------------------------

extern "C" void kernel_launch(void* const* d_in, const int* in_sizes, int n_in,
                              void* d_out, int out_size, void* d_ws, size_t ws_size,
                              hipStream_t stream) {
  const float* x     = (const float*)d_in[0];
  const void*  ei    = d_in[1];
  const float* W1    = (const float*)d_in[2];
  const float* asrc1 = (const float*)d_in[3];
  const float* adst1 = (const float*)d_in[4];
  const float* b1    = (const float*)d_in[5];
  const float* W2    = (const float*)d_in[6];
  const float* asrc2 = (const float*)d_in[7];
  const float* adst2 = (const float*)d_in[8];
  const float* b2    = (const float*)d_in[9];
  const float* gamma = (const float*)d_in[10];
  const float* beta  = (const float*)d_in[11];
  float* out = (float*)d_out;

  const int E0 = in_sizes[1] / 2;       // 800000 raw edges
  const int ET = E0 + NNODES;           // + self loops

  // ws layout (< 88 MB, inside proven-safe >= 90 MB bound).
  //   h2   [0,51.2M)       gemm2..agg2
  //   h1   [25.6M,51.2M)   gemm1..agg1
  //   xb   [51.2M,64M)     conv..gemm1
  //   out1 [51.2M,76.8M)   agg1..gemm2   (xb dead)
  char* w = (char*)d_ws;
  bf16_t* h2     = (bf16_t*)(w + 0);
  bf16_t* h1     = (bf16_t*)(w + 25600000);
  bf16_t* xb     = (bf16_t*)(w + 51200000);
  bf16_t* out1   = (bf16_t*)(w + 51200000);
  bf16_t* Wt1    = (bf16_t*)(w + 76800000);
  bf16_t* Wt2    = (bf16_t*)(w + 76870000);
  float* es1  = (float*)(w + 77200000);
  float* ed1  = (float*)(w + 78000000);
  float* es2  = (float*)(w + 78800000);
  float* ed2  = (float*)(w + 79600000);
  float* m1   = (float*)(w + 80400000);
  float* il1  = (float*)(w + 81200000);
  float* m2   = (float*)(w + 82000000);
  float* il2  = (float*)(w + 82800000);
  int* rowptr = (int*)(w + 83600000);
  int* cursor = (int*)(w + 83800064);
  int* counts = (int*)(w + 84000128);
  int* col    = (int*)(w + 84200192);
  int* bsums  = (int*)(w + 87600192);
  int* boff   = (int*)(w + 87600448);
  int* mode   = (int*)(w + 87600704);

  const int NB = (NNODES + 1023) / 1024;   // 49

  // ---- prep: bf16 conversions ----
  convert_x_kernel<<<(NNODES * 128 / 4 + 255) / 256, 256, 0, stream>>>(x, xb,
                                                                       NNODES * 128 / 4);
  transpose_w_kernel<128, 256><<<256, 128, 0, stream>>>(W1, Wt1);
  transpose_w_kernel<256, 512><<<512, 256, 0, stream>>>(W2, Wt2);

  // ---- edge dtype detect + CSR build ----
  detect_kernel<<<1, 256, 0, stream>>>((const int*)ei, mode);
  zero_kernel<<<(NNODES + 255) / 256, 256, 0, stream>>>(counts, NNODES);
  hist_kernel<<<(ET + 255) / 256, 256, 0, stream>>>(ei, mode, counts, E0, ET);
  scan1_kernel<<<NB, 1024, 0, stream>>>(counts, rowptr, bsums);
  scan2_kernel<<<1, 64, 0, stream>>>(bsums, boff, NB, rowptr, cursor);
  scan3_kernel<<<NB, 1024, 0, stream>>>(boff, rowptr, cursor);
  fill_kernel<<<(ET + 255) / 256, 256, 0, stream>>>(ei, mode, cursor, col, E0, ET);

  const int MB = (NNODES + 63) / 64;       // 782
  const int NODE_BLOCKS = (NNODES + 3) / 4;

  // ---- layer 1 ----
  gemm_mfma_kernel<128, 256><<<dim3(MB, 4), 256, 0, stream>>>(xb, Wt1, h1, NNODES);
  scores1_kernel<<<NODE_BLOCKS, 256, 0, stream>>>(h1, asrc1, adst1, es1, ed1);
  stats_kernel<<<NODE_BLOCKS, 256, 0, stream>>>(es1, ed1, rowptr, col, m1, il1);
  aggregate1_kernel<<<NODE_BLOCKS, 256, 0, stream>>>(h1, es1, ed1, m1, il1,
                                                     rowptr, col, b1, out1);

  // ---- layer 2 ----
  gemm_mfma_kernel<256, 512><<<dim3(MB, 8), 256, 0, stream>>>(out1, Wt2, h2, NNODES);
  scores2_kernel<<<NODE_BLOCKS, 256, 0, stream>>>(h2, asrc2, adst2, es2, ed2);
  stats_kernel<<<NODE_BLOCKS, 256, 0, stream>>>(es2, ed2, rowptr, col, m2, il2);
  aggregate2_ln_kernel<<<NODE_BLOCKS, 256, 0, stream>>>(h2, es2, ed2, m2, il2,
                                                        rowptr, col, b2, gamma, beta, out);
}

// Round 11
// 523.259 us; speedup vs baseline: 1.1402x; 1.0797x over previous
//
#include <hip/hip_runtime.h>
#include <hip/hip_fp16.h>
#include <cstdint>
#include <cstddef>

// ---------------------------------------------------------------------------
// GAT x2 + LayerNorm on MI355X.
// Interface (R0-R7): inputs fp32, edge_index int32, output fp32.
// R8: MFMA bf16 GEMMs.  R11: fp16 per-edge alpha (2-pass, no max-sub),
// bf16x8 single-load gather layout in agg2, unroll x4 in both aggregates.
// ---------------------------------------------------------------------------

constexpr int NNODES = 50000;

typedef unsigned short bf16_t;
typedef __attribute__((ext_vector_type(8))) short bf16x8;
typedef __attribute__((ext_vector_type(4))) float f32x4;

__device__ __forceinline__ float bf2f(bf16_t b) {
  return __uint_as_float(((unsigned int)b) << 16);
}
__device__ __forceinline__ bf16_t f2bf(float f) {
  unsigned int u = __float_as_uint(f);
  u += 0x7fffu + ((u >> 16) & 1u);   // round to nearest even
  return (bf16_t)(u >> 16);
}
__device__ __forceinline__ float4 bf4_to_f4(ushort4 v) {
  return make_float4(bf2f(v.x), bf2f(v.y), bf2f(v.z), bf2f(v.w));
}
__device__ __forceinline__ ushort4 f4_to_bf4(float4 v) {
  return make_ushort4(f2bf(v.x), f2bf(v.y), f2bf(v.z), f2bf(v.w));
}
__device__ __forceinline__ ushort f2h(float f) {
  __half h = __float2half_rn(f);
  return *(ushort*)&h;
}
__device__ __forceinline__ float h2f(ushort u) {
  __half h; *(ushort*)&h = u;
  return __half2float(h);
}
__device__ __forceinline__ float lrelu(float x) { return x > 0.f ? x : 0.2f * x; }
__device__ __forceinline__ int clampi(int v, int lo, int hi) {
  return v < lo ? lo : (v > hi ? hi : v);
}
__device__ __forceinline__ int load_edge(const void* ei, int mode, int idx) {
  if (mode) return (int)((const long long*)ei)[idx];
  return ((const int*)ei)[idx];
}

// ------------------------------ prep kernels -------------------------------

__global__ void convert_x_kernel(const float* __restrict__ x, bf16_t* __restrict__ xb,
                                 int n4) {
  int i = blockIdx.x * blockDim.x + threadIdx.x;
  if (i >= n4) return;
  float4 v = *(const float4*)(x + 4 * (size_t)i);
  *(ushort4*)(xb + 4 * (size_t)i) = f4_to_bf4(v);
}

template <int K, int NC>
__global__ void transpose_w_kernel(const float* __restrict__ W, bf16_t* __restrict__ Wt) {
  int n = blockIdx.x;
  int k = threadIdx.x;
  Wt[(size_t)n * K + k] = f2bf(W[(size_t)k * NC + n]);
}

// --------------------------- edge dtype detection --------------------------
__global__ void detect_kernel(const int* __restrict__ ei32, int* __restrict__ mode) {
  __shared__ int nz;
  if (threadIdx.x == 0) nz = 0;
  __syncthreads();
  int idx = 2 * threadIdx.x + 1;
  if (ei32[idx] != 0) atomicAdd(&nz, 1);
  __syncthreads();
  if (threadIdx.x == 0) mode[0] = (nz == 0) ? 1 : 0;
}

// ------------------------------- CSR build ---------------------------------

__global__ void zero_kernel(int* __restrict__ p, int n) {
  int i = blockIdx.x * blockDim.x + threadIdx.x;
  if (i < n) p[i] = 0;
}

__global__ void hist_kernel(const void* __restrict__ ei, const int* __restrict__ modep,
                            int* __restrict__ counts, int e0, int et) {
  int e = blockIdx.x * blockDim.x + threadIdx.x;
  if (e >= et) return;
  int mode = modep[0];
  int dst = (e < e0) ? load_edge(ei, mode, e0 + e) : (e - e0);
  dst = clampi(dst, 0, NNODES - 1);
  atomicAdd(&counts[dst], 1);
}

__global__ __launch_bounds__(1024) void scan1_kernel(const int* __restrict__ counts,
                                                     int* __restrict__ rowptr,
                                                     int* __restrict__ bsums) {
  __shared__ int sm[1024];
  int t = threadIdx.x;
  int i = blockIdx.x * 1024 + t;
  sm[t] = (i < NNODES) ? counts[i] : 0;
  __syncthreads();
  for (int off = 1; off < 1024; off <<= 1) {
    int u = (t >= off) ? sm[t - off] : 0;
    __syncthreads();
    sm[t] += u;
    __syncthreads();
  }
  if (i < NNODES) rowptr[i + 1] = sm[t];
  if (t == 1023) bsums[blockIdx.x] = sm[1023];
}

__global__ void scan2_kernel(const int* __restrict__ bsums, int* __restrict__ boff,
                             int nb, int* __restrict__ rowptr, int* __restrict__ cursor) {
  if (threadIdx.x == 0 && blockIdx.x == 0) {
    int run = 0;
    for (int b = 0; b < nb; ++b) { boff[b] = run; run += bsums[b]; }
    rowptr[0] = 0;
    cursor[0] = 0;
  }
}

__global__ __launch_bounds__(1024) void scan3_kernel(const int* __restrict__ boff,
                                                     int* __restrict__ rowptr,
                                                     int* __restrict__ cursor) {
  int i = blockIdx.x * 1024 + threadIdx.x;
  if (i < NNODES) {
    int v = rowptr[i + 1] + boff[blockIdx.x];
    rowptr[i + 1] = v;
    cursor[i + 1] = v;
  }
}

__global__ void fill_kernel(const void* __restrict__ ei, const int* __restrict__ modep,
                            int* __restrict__ cursor, int* __restrict__ col,
                            int e0, int et) {
  int e = blockIdx.x * blockDim.x + threadIdx.x;
  if (e >= et) return;
  int mode = modep[0];
  int src, dst;
  if (e < e0) { src = load_edge(ei, mode, e); dst = load_edge(ei, mode, e0 + e); }
  else        { src = dst = e - e0; }
  src = clampi(src, 0, NNODES - 1);
  dst = clampi(dst, 0, NNODES - 1);
  int pos = atomicAdd(&cursor[dst], 1);
  col[pos] = src;
}

// ------------------------------ MFMA GEMM ----------------------------------
template <int K, int NC>
__global__ __launch_bounds__(256) void gemm_mfma_kernel(const bf16_t* __restrict__ A,
                                                        const bf16_t* __restrict__ Wt,
                                                        bf16_t* __restrict__ C, int M) {
  __shared__ __align__(16) ushort As[64 * 40];
  __shared__ __align__(16) ushort Bs[64 * 40];
  const int t    = threadIdx.x;
  const int wv   = t >> 6;
  const int lane = t & 63;
  const int m    = lane & 15;
  const int quad = lane >> 4;
  const int bm = blockIdx.x * 64, bn = blockIdx.y * 64;
  const int srow = t & 63;
  const int sk8  = t >> 6;

  f32x4 acc0 = {0.f, 0.f, 0.f, 0.f};
  f32x4 acc1 = {0.f, 0.f, 0.f, 0.f};
  f32x4 acc2 = {0.f, 0.f, 0.f, 0.f};
  f32x4 acc3 = {0.f, 0.f, 0.f, 0.f};

  for (int k0 = 0; k0 < K; k0 += 32) {
    int ga = clampi(bm + srow, 0, M - 1);
    float4 av = *(const float4*)(A + (size_t)ga * K + k0 + sk8 * 8);
    *(float4*)(&As[srow * 40 + sk8 * 8]) = av;
    float4 bv = *(const float4*)(Wt + (size_t)(bn + srow) * K + k0 + sk8 * 8);
    *(float4*)(&Bs[srow * 40 + sk8 * 8]) = bv;
    __syncthreads();

    bf16x8 af = *(const bf16x8*)(&As[(wv * 16 + m) * 40 + quad * 8]);
    bf16x8 b0 = *(const bf16x8*)(&Bs[(0 * 16 + m) * 40 + quad * 8]);
    bf16x8 b1 = *(const bf16x8*)(&Bs[(1 * 16 + m) * 40 + quad * 8]);
    bf16x8 b2 = *(const bf16x8*)(&Bs[(2 * 16 + m) * 40 + quad * 8]);
    bf16x8 b3 = *(const bf16x8*)(&Bs[(3 * 16 + m) * 40 + quad * 8]);
    acc0 = __builtin_amdgcn_mfma_f32_16x16x32_bf16(af, b0, acc0, 0, 0, 0);
    acc1 = __builtin_amdgcn_mfma_f32_16x16x32_bf16(af, b1, acc1, 0, 0, 0);
    acc2 = __builtin_amdgcn_mfma_f32_16x16x32_bf16(af, b2, acc2, 0, 0, 0);
    acc3 = __builtin_amdgcn_mfma_f32_16x16x32_bf16(af, b3, acc3, 0, 0, 0);
    __syncthreads();
  }

#pragma unroll
  for (int r = 0; r < 4; ++r) {
    int row = bm + wv * 16 + quad * 4 + r;
    if (row < M) {
      size_t base = (size_t)row * NC + bn;
      C[base +  0 + m] = f2bf(acc0[r]);
      C[base + 16 + m] = f2bf(acc1[r]);
      C[base + 32 + m] = f2bf(acc2[r]);
      C[base + 48 + m] = f2bf(acc3[r]);
    }
  }
}

// ------------------------------ attention scores ---------------------------
__global__ __launch_bounds__(256) void scores1_kernel(const bf16_t* __restrict__ h,
                                                      const float* __restrict__ asrc,
                                                      const float* __restrict__ adst,
                                                      float* __restrict__ es,
                                                      float* __restrict__ ed) {
  int node = (blockIdx.x * blockDim.x + threadIdx.x) >> 6;
  if (node >= NNODES) return;
  int lane = threadIdx.x & 63;
  float4 hv = bf4_to_f4(*(const ushort4*)(h + (size_t)node * 256 + 4 * lane));
  float4 av = *(const float4*)(asrc + 4 * lane);
  float4 dv = *(const float4*)(adst + 4 * lane);
  float ps = hv.x * av.x + hv.y * av.y + hv.z * av.z + hv.w * av.w;
  float pd = hv.x * dv.x + hv.y * dv.y + hv.z * dv.z + hv.w * dv.w;
  for (int m = 1; m < 16; m <<= 1) { ps += __shfl_xor(ps, m); pd += __shfl_xor(pd, m); }
  if ((lane & 15) == 0) {
    es[node * 4 + (lane >> 4)] = ps;
    ed[node * 4 + (lane >> 4)] = pd;
  }
}

__global__ __launch_bounds__(256) void scores2_kernel(const bf16_t* __restrict__ h,
                                                      const float* __restrict__ asrc,
                                                      const float* __restrict__ adst,
                                                      float* __restrict__ es,
                                                      float* __restrict__ ed) {
  int node = (blockIdx.x * blockDim.x + threadIdx.x) >> 6;
  if (node >= NNODES) return;
  int lane = threadIdx.x & 63;
  float4 hA = bf4_to_f4(*(const ushort4*)(h + (size_t)node * 512 + 4 * lane));
  float4 hB = bf4_to_f4(*(const ushort4*)(h + (size_t)node * 512 + 4 * lane + 256));
  float4 aA = *(const float4*)(asrc + 4 * lane);
  float4 aB = *(const float4*)(asrc + 4 * lane + 256);
  float4 dA = *(const float4*)(adst + 4 * lane);
  float4 dB = *(const float4*)(adst + 4 * lane + 256);
  float psA = hA.x * aA.x + hA.y * aA.y + hA.z * aA.z + hA.w * aA.w;
  float psB = hB.x * aB.x + hB.y * aB.y + hB.z * aB.z + hB.w * aB.w;
  float pdA = hA.x * dA.x + hA.y * dA.y + hA.z * dA.z + hA.w * dA.w;
  float pdB = hB.x * dB.x + hB.y * dB.y + hB.z * dB.z + hB.w * dB.w;
  for (int m = 1; m < 32; m <<= 1) {
    psA += __shfl_xor(psA, m); psB += __shfl_xor(psB, m);
    pdA += __shfl_xor(pdA, m); pdB += __shfl_xor(pdB, m);
  }
  if ((lane & 31) == 0) {
    int g = lane >> 5;
    es[node * 4 + g]     = psA;  es[node * 4 + g + 2] = psB;
    ed[node * 4 + g]     = pdA;  ed[node * 4 + g + 2] = pdB;
  }
}

// --------------------------- alpha precompute (fp16) -----------------------
// wave per node; lanes edge-parallel; 2 passes (no max-sub: |e| <= ~10).
// alpha[p] = half4( exp(e_h) / (sum_exp_h + 1e-16) ), p = CSR position.
__global__ __launch_bounds__(256) void alpha_kernel(
    const float* __restrict__ es, const float* __restrict__ ed,
    const int* __restrict__ rowptr, const int* __restrict__ col,
    ushort* __restrict__ alpha) {
  int node = (blockIdx.x * blockDim.x + threadIdx.x) >> 6;
  if (node >= NNODES) return;
  int lane = threadIdx.x & 63;
  int beg = rowptr[node], end = rowptr[node + 1];
  float4 edv = *(const float4*)(ed + node * 4);
  float4 l = make_float4(0.f, 0.f, 0.f, 0.f);
  for (int p = beg + lane; p < end; p += 64) {
    int s = col[p];
    float4 e = *(const float4*)(es + s * 4);
    l.x += __expf(lrelu(e.x + edv.x));
    l.y += __expf(lrelu(e.y + edv.y));
    l.z += __expf(lrelu(e.z + edv.z));
    l.w += __expf(lrelu(e.w + edv.w));
  }
  for (int off = 1; off < 64; off <<= 1) {
    l.x += __shfl_xor(l.x, off);
    l.y += __shfl_xor(l.y, off);
    l.z += __shfl_xor(l.z, off);
    l.w += __shfl_xor(l.w, off);
  }
  float4 il = make_float4(1.f / (l.x + 1e-16f), 1.f / (l.y + 1e-16f),
                          1.f / (l.z + 1e-16f), 1.f / (l.w + 1e-16f));
  for (int p = beg + lane; p < end; p += 64) {
    int s = col[p];
    float4 e = *(const float4*)(es + s * 4);
    ushort4 a;
    a.x = f2h(__expf(lrelu(e.x + edv.x)) * il.x);
    a.y = f2h(__expf(lrelu(e.y + edv.y)) * il.y);
    a.z = f2h(__expf(lrelu(e.z + edv.z)) * il.z);
    a.w = f2h(__expf(lrelu(e.w + edv.w)) * il.w);
    *(ushort4*)(alpha + (size_t)p * 4) = a;
  }
}

// ------------------------------- aggregation -------------------------------
// layer 1: wave per node; lane holds 4 channels at 4*lane (head = lane>>4).
// Pure gather: acc += alpha[j,head] * h1[src]. Unrolled x4, loads hoisted.
__global__ __launch_bounds__(256) void aggregate1_kernel(
    const bf16_t* __restrict__ h, const ushort* __restrict__ alpha,
    const int* __restrict__ rowptr, const int* __restrict__ col,
    const float* __restrict__ b1, bf16_t* __restrict__ out) {
  int node = (blockIdx.x * blockDim.x + threadIdx.x) >> 6;
  if (node >= NNODES) return;
  int lane = threadIdx.x & 63;
  int head = lane >> 4;
  int beg = rowptr[node], end = rowptr[node + 1];
  const ushort4* hb = (const ushort4*)h;   // row = 64 ushort4
  float4 acc = make_float4(0.f, 0.f, 0.f, 0.f);
  int j = beg;
  for (; j + 4 <= end; j += 4) {
    int s0 = col[j], s1 = col[j + 1], s2 = col[j + 2], s3 = col[j + 3];
    ushort u0 = alpha[(size_t)(j + 0) * 4 + head];
    ushort u1 = alpha[(size_t)(j + 1) * 4 + head];
    ushort u2 = alpha[(size_t)(j + 2) * 4 + head];
    ushort u3 = alpha[(size_t)(j + 3) * 4 + head];
    ushort4 r0 = hb[(size_t)s0 * 64 + lane];
    ushort4 r1 = hb[(size_t)s1 * 64 + lane];
    ushort4 r2 = hb[(size_t)s2 * 64 + lane];
    ushort4 r3 = hb[(size_t)s3 * 64 + lane];
    float a0 = h2f(u0), a1 = h2f(u1), a2 = h2f(u2), a3 = h2f(u3);
    float4 v0 = bf4_to_f4(r0), v1 = bf4_to_f4(r1);
    float4 v2 = bf4_to_f4(r2), v3 = bf4_to_f4(r3);
    acc.x += a0 * v0.x + a1 * v1.x + a2 * v2.x + a3 * v3.x;
    acc.y += a0 * v0.y + a1 * v1.y + a2 * v2.y + a3 * v3.y;
    acc.z += a0 * v0.z + a1 * v1.z + a2 * v2.z + a3 * v3.z;
    acc.w += a0 * v0.w + a1 * v1.w + a2 * v2.w + a3 * v3.w;
  }
  for (; j < end; ++j) {
    int s0 = col[j];
    float a0 = h2f(alpha[(size_t)j * 4 + head]);
    float4 v0 = bf4_to_f4(hb[(size_t)s0 * 64 + lane]);
    acc.x += a0 * v0.x;
    acc.y += a0 * v0.y;
    acc.z += a0 * v0.z;
    acc.w += a0 * v0.w;
  }
  float4 bb = *(const float4*)(b1 + 4 * lane);
  float4 o;
  o.x = fmaxf(acc.x + bb.x, 0.f);
  o.y = fmaxf(acc.y + bb.y, 0.f);
  o.z = fmaxf(acc.z + bb.z, 0.f);
  o.w = fmaxf(acc.w + bb.w, 0.f);
  *(ushort4*)(out + (size_t)node * 256 + 4 * lane) = f4_to_bf4(o);
}

// layer 2: wave per node; lane covers 8 consecutive channels [8*lane, 8*lane+8)
// of the 512-ch h2 row -> ONE bf16x8 (16B) load per edge per lane; lane's head
// = lane>>4 -> one alpha per edge. Head-mean = shfl_xor 16 + 32; then +b2,
// LayerNorm over 128, fp32 store (lanes 0-15).
__global__ __launch_bounds__(256) void aggregate2_ln_kernel(
    const bf16_t* __restrict__ h, const ushort* __restrict__ alpha,
    const int* __restrict__ rowptr, const int* __restrict__ col,
    const float* __restrict__ b2, const float* __restrict__ gamma,
    const float* __restrict__ beta, float* __restrict__ out) {
  int node = (blockIdx.x * blockDim.x + threadIdx.x) >> 6;
  if (node >= NNODES) return;
  int lane = threadIdx.x & 63;
  int head = lane >> 4;
  int beg = rowptr[node], end = rowptr[node + 1];
  const bf16x8* hb = (const bf16x8*)h;   // row = 64 bf16x8 chunks
  float acc[8] = {0.f, 0.f, 0.f, 0.f, 0.f, 0.f, 0.f, 0.f};
  int j = beg;
  for (; j + 4 <= end; j += 4) {
    int s0 = col[j], s1 = col[j + 1], s2 = col[j + 2], s3 = col[j + 3];
    ushort u0 = alpha[(size_t)(j + 0) * 4 + head];
    ushort u1 = alpha[(size_t)(j + 1) * 4 + head];
    ushort u2 = alpha[(size_t)(j + 2) * 4 + head];
    ushort u3 = alpha[(size_t)(j + 3) * 4 + head];
    bf16x8 r0 = hb[(size_t)s0 * 64 + lane];
    bf16x8 r1 = hb[(size_t)s1 * 64 + lane];
    bf16x8 r2 = hb[(size_t)s2 * 64 + lane];
    bf16x8 r3 = hb[(size_t)s3 * 64 + lane];
    float a0 = h2f(u0), a1 = h2f(u1), a2 = h2f(u2), a3 = h2f(u3);
#pragma unroll
    for (int i = 0; i < 8; ++i) {
      acc[i] += a0 * bf2f((ushort)r0[i]) + a1 * bf2f((ushort)r1[i]) +
                a2 * bf2f((ushort)r2[i]) + a3 * bf2f((ushort)r3[i]);
    }
  }
  for (; j < end; ++j) {
    int s0 = col[j];
    float a0 = h2f(alpha[(size_t)j * 4 + head]);
    bf16x8 r0 = hb[(size_t)s0 * 64 + lane];
#pragma unroll
    for (int i = 0; i < 8; ++i) acc[i] += a0 * bf2f((ushort)r0[i]);
  }
  // head-mean: lanes g, g^16, g^32, g^48 hold channels h*128 + [8g,8g+8)
#pragma unroll
  for (int i = 0; i < 8; ++i) {
    acc[i] += __shfl_xor(acc[i], 16);
    acc[i] += __shfl_xor(acc[i], 32);
  }
  int g = lane & 15;                 // channel group: channels [8g, 8g+8)
  float4 bA = *(const float4*)(b2 + 8 * g);
  float4 bB = *(const float4*)(b2 + 8 * g + 4);
  float s[8];
  s[0] = acc[0] * 0.25f + bA.x;  s[1] = acc[1] * 0.25f + bA.y;
  s[2] = acc[2] * 0.25f + bA.z;  s[3] = acc[3] * 0.25f + bA.w;
  s[4] = acc[4] * 0.25f + bB.x;  s[5] = acc[5] * 0.25f + bB.y;
  s[6] = acc[6] * 0.25f + bB.z;  s[7] = acc[7] * 0.25f + bB.w;
  float part = s[0] + s[1] + s[2] + s[3] + s[4] + s[5] + s[6] + s[7];
  for (int m = 1; m < 16; m <<= 1) part += __shfl_xor(part, m);
  float mu = part * (1.f / 128.f);
  float sq = 0.f;
  float d[8];
#pragma unroll
  for (int i = 0; i < 8; ++i) { d[i] = s[i] - mu; sq += d[i] * d[i]; }
  for (int m = 1; m < 16; m <<= 1) sq += __shfl_xor(sq, m);
  float r = rsqrtf(sq * (1.f / 128.f) + 1e-5f);
  float4 gA = *(const float4*)(gamma + 8 * g);
  float4 gB = *(const float4*)(gamma + 8 * g + 4);
  float4 tA = *(const float4*)(beta + 8 * g);
  float4 tB = *(const float4*)(beta + 8 * g + 4);
  if (lane < 16) {
    float4 oA, oB;
    oA.x = d[0] * r * gA.x + tA.x;  oA.y = d[1] * r * gA.y + tA.y;
    oA.z = d[2] * r * gA.z + tA.z;  oA.w = d[3] * r * gA.w + tA.w;
    oB.x = d[4] * r * gB.x + tB.x;  oB.y = d[5] * r * gB.y + tB.y;
    oB.z = d[6] * r * gB.z + tB.z;  oB.w = d[7] * r * gB.w + tB.w;
    *(float4*)(out + (size_t)node * 128 + 8 * g)     = oA;
    *(float4*)(out + (size_t)node * 128 + 8 * g + 4) = oB;
  }
}

// ------------------------------- launcher ----------------------------------

extern "C" void kernel_launch(void* const* d_in, const int* in_sizes, int n_in,
                              void* d_out, int out_size, void* d_ws, size_t ws_size,
                              hipStream_t stream) {
  const float* x     = (const float*)d_in[0];
  const void*  ei    = d_in[1];
  const float* W1    = (const float*)d_in[2];
  const float* asrc1 = (const float*)d_in[3];
  const float* adst1 = (const float*)d_in[4];
  const float* b1    = (const float*)d_in[5];
  const float* W2    = (const float*)d_in[6];
  const float* asrc2 = (const float*)d_in[7];
  const float* adst2 = (const float*)d_in[8];
  const float* b2    = (const float*)d_in[9];
  const float* gamma = (const float*)d_in[10];
  const float* beta  = (const float*)d_in[11];
  float* out = (float*)d_out;

  const int E0 = in_sizes[1] / 2;       // 800000 raw edges
  const int ET = E0 + NNODES;           // + self loops

  // ws layout (< 89.7 MB, inside proven-safe >= 90 MB bound). Overlays:
  //   h2    [0,51.2M)       gemm2..agg2
  //   h1    [25.6M,51.2M)   gemm1..agg1
  //   xb    [51.2M,64M)     conv..gemm1
  //   out1  [51.2M,76.8M)   agg1..gemm2
  //   alpha [76.8M,83.6M)   alpha1..agg1, reused alpha2..agg2 (fp16 half4)
  //   es/ed single slots    scores_i..alpha_i (layer-sequential reuse)
  char* w = (char*)d_ws;
  bf16_t* h2     = (bf16_t*)(w + 0);
  bf16_t* h1     = (bf16_t*)(w + 25600000);
  bf16_t* xb     = (bf16_t*)(w + 51200000);
  bf16_t* out1   = (bf16_t*)(w + 51200000);
  ushort* alpha  = (ushort*)(w + 76800000);   // 850000*8 = 6.8 MB
  float* es    = (float*)(w + 83600000);      // 800 KB
  float* ed    = (float*)(w + 84400000);      // 800 KB
  bf16_t* Wt1    = (bf16_t*)(w + 85200000);   // 64 KB
  bf16_t* Wt2    = (bf16_t*)(w + 85300000);   // 256 KB
  int* rowptr = (int*)(w + 85600000);
  int* cursor = (int*)(w + 85800064);
  int* counts = (int*)(w + 86000128);
  int* col    = (int*)(w + 86200192);         // 3.4 MB
  int* bsums  = (int*)(w + 89600192);
  int* boff   = (int*)(w + 89600448);
  int* mode   = (int*)(w + 89600704);

  const int NB = (NNODES + 1023) / 1024;   // 49

  // ---- prep: bf16 conversions ----
  convert_x_kernel<<<(NNODES * 128 / 4 + 255) / 256, 256, 0, stream>>>(x, xb,
                                                                       NNODES * 128 / 4);
  transpose_w_kernel<128, 256><<<256, 128, 0, stream>>>(W1, Wt1);
  transpose_w_kernel<256, 512><<<512, 256, 0, stream>>>(W2, Wt2);

  // ---- edge dtype detect + CSR build ----
  detect_kernel<<<1, 256, 0, stream>>>((const int*)ei, mode);
  zero_kernel<<<(NNODES + 255) / 256, 256, 0, stream>>>(counts, NNODES);
  hist_kernel<<<(ET + 255) / 256, 256, 0, stream>>>(ei, mode, counts, E0, ET);
  scan1_kernel<<<NB, 1024, 0, stream>>>(counts, rowptr, bsums);
  scan2_kernel<<<1, 64, 0, stream>>>(bsums, boff, NB, rowptr, cursor);
  scan3_kernel<<<NB, 1024, 0, stream>>>(boff, rowptr, cursor);
  fill_kernel<<<(ET + 255) / 256, 256, 0, stream>>>(ei, mode, cursor, col, E0, ET);

  const int MB = (NNODES + 63) / 64;       // 782
  const int NODE_BLOCKS = (NNODES + 3) / 4;

  // ---- layer 1 ----
  gemm_mfma_kernel<128, 256><<<dim3(MB, 4), 256, 0, stream>>>(xb, Wt1, h1, NNODES);
  scores1_kernel<<<NODE_BLOCKS, 256, 0, stream>>>(h1, asrc1, adst1, es, ed);
  alpha_kernel<<<NODE_BLOCKS, 256, 0, stream>>>(es, ed, rowptr, col, alpha);
  aggregate1_kernel<<<NODE_BLOCKS, 256, 0, stream>>>(h1, alpha, rowptr, col, b1, out1);

  // ---- layer 2 ----
  gemm_mfma_kernel<256, 512><<<dim3(MB, 8), 256, 0, stream>>>(out1, Wt2, h2, NNODES);
  scores2_kernel<<<NODE_BLOCKS, 256, 0, stream>>>(h2, asrc2, adst2, es, ed);
  alpha_kernel<<<NODE_BLOCKS, 256, 0, stream>>>(es, ed, rowptr, col, alpha);
  aggregate2_ln_kernel<<<NODE_BLOCKS, 256, 0, stream>>>(h2, alpha, rowptr, col,
                                                        b2, gamma, beta, out);
}